// Round 6
// baseline (427.257 us; speedup 1.0000x reference)
//
#include <hip/hip_runtime.h>

// Qwen3 MoE experts: per-expert SwiGLU MLP.
//   gate = rin @ gate_proj^T ; up = rin @ up_proj^T
//   hidden = silu(gate) * up ; out = hidden @ down_proj^T
// E=32, T=512, H=2048, I=768. f32 inputs; bf16 MFMA, f32 accum.
// ws: hidden [E][T][I] bf16 = 24 MB.
//
// R5: gateup rebuilt on the proven moe_down structure: global_load_lds f32
//     + double buffer + counted vmcnt + >=2 blocks/CU. BK=16 so the dbuf
//     fits 48 KB; mfma_f32_32x32x16_bf16 (K=16/step). Chunk swizzle
//     p=(c+(r>>3))&3 (inverse applied on global source, rule #21) makes
//     the stride-64B fragment reads bank-conflict-free.
//     moe_down unchanged (it runs at ~605 TF effective).

#define NE 32
#define NT 512
#define NH 2048
#define NI 768

typedef short        short8   __attribute__((ext_vector_type(8)));
typedef float        floatx4  __attribute__((ext_vector_type(4)));
typedef float        floatx16 __attribute__((ext_vector_type(16)));
typedef __attribute__((address_space(1))) const unsigned int g_u32;
typedef __attribute__((address_space(3))) unsigned int l_u32;

__device__ __forceinline__ void gl_lds16(const void* g, void* l) {
    __builtin_amdgcn_global_load_lds((g_u32*)g, (l_u32*)l, 16, 0, 0);
}

__device__ __forceinline__ unsigned int cvt_pk_bf16(float lo, float hi) {
    unsigned int r;
    asm("v_cvt_pk_bf16_f32 %0, %1, %2" : "=v"(r) : "v"(lo), "v"(hi));
    return r;
}

// two f32x4 (8 consecutive K values) -> one bf16x8 MFMA fragment
__device__ __forceinline__ short8 frag8(floatx4 x0, floatx4 x1) {
    union { unsigned int u[4]; short8 s; } t;
    t.u[0] = cvt_pk_bf16(x0[0], x0[1]);
    t.u[1] = cvt_pk_bf16(x0[2], x0[3]);
    t.u[2] = cvt_pk_bf16(x1[0], x1[1]);
    t.u[3] = cvt_pk_bf16(x1[2], x1[3]);
    return t.s;
}

__device__ __forceinline__ ushort f2bf(float f) {
    union { float f; unsigned int u; } v; v.f = f;
    unsigned int r = v.u + 0x7fffu + ((v.u >> 16) & 1u);
    return (ushort)(r >> 16);
}

// ---------------------------------------------------------------------------
// Kernel 1: fused gate+up + SwiGLU -> hidden(bf16).
// BM=128(T) x BN=128(I), BK=16 over H; 4 waves (2x2), each wave 64x64/GEMM
// as 2x2 frags of mfma_f32_32x32x16_bf16.
// LDS: 2 bufs x 3 x f32[128][16] = 48 KB -> 2 blocks/CU.
// Tile row = 64B = 4 chunks of 16B; physical chunk p = (c + (r>>3)) & 3.
// ---------------------------------------------------------------------------
__global__ __launch_bounds__(256, 2) void moe_gateup(
    const float* __restrict__ rin, const float* __restrict__ gate,
    const float* __restrict__ up, ushort* __restrict__ hidden)
{
    __shared__ float As[2][128][16];
    __shared__ float Gs[2][128][16];
    __shared__ float Us[2][128][16];

    const int bid = blockIdx.x;
    const int wg  = (bid & 7) * (768 / 8) + (bid >> 3);
    const int e   = wg / 24;
    const int rem = wg % 24;
    const int ti  = rem % 6;
    const int tm  = rem / 6;

    const int tid  = threadIdx.x;
    const int lane = tid & 63;
    const int wave = tid >> 6;
    const int wr = wave >> 1, wc = wave & 1;

    const float* Ab = rin  + (size_t)e * NT * NH + (size_t)(tm * 128) * NH;
    const float* Gb = gate + (size_t)e * NI * NH + (size_t)(ti * 128) * NH;
    const float* Ub = up   + (size_t)e * NI * NH + (size_t)(ti * 128) * NH;

    floatx16 accg[2][2], accu[2][2];
    #pragma unroll
    for (int m = 0; m < 2; ++m)
        #pragma unroll
        for (int n = 0; n < 2; ++n) {
            accg[m][n] = (floatx16)0.f;
            accu[m][n] = (floatx16)0.f;
        }

    const int rA    = lane & 31;     // row within 32-row fragment
    const int khalf = lane >> 5;     // which 8-wide K half
    const int KT = NH / 16;          // 128 iterations

    // 6 gl_lds per wave per stage (2 insts x 3 tiles); inst covers 16 rows.
#define STAGE_GU(kt, b) do {                                                 \
        const int k0_ = (kt) * 16;                                           \
        _Pragma("unroll")                                                    \
        for (int i = 0; i < 2; ++i) {                                        \
            const int g_ = wave * 2 + i;                                     \
            const int r_ = g_ * 16 + (lane >> 2);                            \
            const int lc_ = ((lane & 3) - (r_ >> 3)) & 3;                    \
            const size_t so_ = (size_t)r_ * NH + k0_ + lc_ * 4;              \
            gl_lds16(Ab + so_, &As[b][g_ * 16][0]);                          \
            gl_lds16(Gb + so_, &Gs[b][g_ * 16][0]);                          \
            gl_lds16(Ub + so_, &Us[b][g_ * 16][0]);                          \
        }                                                                    \
    } while (0)

    STAGE_GU(0, 0);

    for (int kt = 0; kt < KT; ++kt) {
        const int cur = kt & 1;
        if (kt + 1 < KT) {
            STAGE_GU(kt + 1, cur ^ 1);
            asm volatile("s_waitcnt vmcnt(6)" ::: "memory");   // tile kt landed
        } else {
            asm volatile("s_waitcnt vmcnt(0)" ::: "memory");
        }
        __builtin_amdgcn_s_barrier();

        short8 af[2], gf[2], uf[2];
        #pragma unroll
        for (int m = 0; m < 2; ++m) {
            const int r = wr * 64 + m * 32 + rA;
            const int p0 = (2 * khalf     + (r >> 3)) & 3;
            const int p1 = (2 * khalf + 1 + (r >> 3)) & 3;
            af[m] = frag8(*(const floatx4*)&As[cur][r][p0 * 4],
                          *(const floatx4*)&As[cur][r][p1 * 4]);
        }
        #pragma unroll
        for (int n = 0; n < 2; ++n) {
            const int r = wc * 64 + n * 32 + rA;
            const int p0 = (2 * khalf     + (r >> 3)) & 3;
            const int p1 = (2 * khalf + 1 + (r >> 3)) & 3;
            gf[n] = frag8(*(const floatx4*)&Gs[cur][r][p0 * 4],
                          *(const floatx4*)&Gs[cur][r][p1 * 4]);
            uf[n] = frag8(*(const floatx4*)&Us[cur][r][p0 * 4],
                          *(const floatx4*)&Us[cur][r][p1 * 4]);
        }
        #pragma unroll
        for (int m = 0; m < 2; ++m)
            #pragma unroll
            for (int n = 0; n < 2; ++n) {
                accg[m][n] = __builtin_amdgcn_mfma_f32_32x32x16_bf16(
                    af[m], gf[n], accg[m][n], 0, 0, 0);
                accu[m][n] = __builtin_amdgcn_mfma_f32_32x32x16_bf16(
                    af[m], uf[n], accu[m][n], 0, 0, 0);
            }

        asm volatile("s_waitcnt lgkmcnt(0)" ::: "memory");
        __builtin_amdgcn_sched_barrier(0);
        __builtin_amdgcn_s_barrier();
    }
#undef STAGE_GU

    // Epilogue: silu(g)*u -> bf16. 32x32 C/D layout (m74/m101):
    // col = lane&31, row = (reg&3) + 8*(reg>>2) + 4*(lane>>5).
    const int ccol  = lane & 31;
    const int rbase = 4 * (lane >> 5);
    const size_t hbase = ((size_t)e * NT + (size_t)tm * 128) * NI + ti * 128;
    #pragma unroll
    for (int m = 0; m < 2; ++m)
        #pragma unroll
        for (int n = 0; n < 2; ++n)
            #pragma unroll
            for (int jr = 0; jr < 16; ++jr) {
                const float g = accg[m][n][jr];
                const float u = accu[m][n][jr];
                const float hh = (g / (1.f + __expf(-g))) * u;
                const int row = wr * 64 + m * 32 + rbase + (jr & 3) + 8 * (jr >> 2);
                const int col = wc * 64 + n * 32 + ccol;
                hidden[hbase + (size_t)row * NI + col] = f2bf(hh);
            }
}

// ---------------------------------------------------------------------------
// Kernel 2: down projection (unchanged — gl_lds dbuf, ~605 TF effective).
// A = hidden [T,I] bf16, B = down [H,I] f32. LDS 48 KB.
// ---------------------------------------------------------------------------
__global__ __launch_bounds__(256, 2) void moe_down(
    const ushort* __restrict__ hidden, const float* __restrict__ down,
    float* __restrict__ out)
{
    __shared__ ushort As[2][128][32];
    __shared__ float  Bs[2][128][32];

    const int bid = blockIdx.x;
    const int wg  = (bid & 7) * (2048 / 8) + (bid >> 3);
    const int e   = wg >> 6;
    const int rem = wg & 63;
    const int tn  = rem & 15;
    const int tm  = rem >> 4;

    const int tid  = threadIdx.x;
    const int lane = tid & 63;
    const int wave = tid >> 6;
    const int wr = wave >> 1, wc = wave & 1;

    const ushort* Ab = hidden + ((size_t)e * NT + (size_t)tm * 128) * NI;
    const float*  Bb = down + (size_t)e * NH * NI + (size_t)(tn * 128) * NI;

    floatx4 acc[4][4];
    #pragma unroll
    for (int m = 0; m < 4; ++m)
        #pragma unroll
        for (int n = 0; n < 4; ++n) acc[m][n] = (floatx4)0.f;

    const int frow = lane & 15;
    const int h    = lane >> 4;
    const int ca   = h ^ (frow & 3);
    const int rb   = frow & 7;
    const int c0   = (2 * h) ^ rb;
    const int c1   = (2 * h + 1) ^ rb;
    const int KT = NI / 32;

#define STAGE_DN(kt, b) do {                                                 \
        const int k0_ = (kt) * 32;                                           \
        _Pragma("unroll")                                                    \
        for (int i = 0; i < 2; ++i) {                                        \
            const int g_ = wave * 2 + i;                                     \
            const int r_ = g_ * 16 + (lane >> 2);                            \
            const int cs_ = (lane & 3) ^ (r_ & 3);                           \
            gl_lds16(Ab + (size_t)r_ * NI + k0_ + cs_ * 8, &As[b][g_ * 16][0]); \
        }                                                                    \
        _Pragma("unroll")                                                    \
        for (int i = 0; i < 4; ++i) {                                        \
            const int g_ = wave * 4 + i;                                     \
            const int r_ = g_ * 8 + (lane >> 3);                             \
            const int cs_ = (lane & 7) ^ (r_ & 7);                           \
            gl_lds16(Bb + (size_t)r_ * NI + k0_ + cs_ * 4, &Bs[b][g_ * 8][0]); \
        }                                                                    \
    } while (0)

    STAGE_DN(0, 0);

    for (int kt = 0; kt < KT; ++kt) {
        const int cur = kt & 1;
        if (kt + 1 < KT) {
            STAGE_DN(kt + 1, cur ^ 1);
            asm volatile("s_waitcnt vmcnt(6)" ::: "memory");
        } else {
            asm volatile("s_waitcnt vmcnt(0)" ::: "memory");
        }
        __builtin_amdgcn_s_barrier();

        short8 af[4], bf[4];
        #pragma unroll
        for (int m = 0; m < 4; ++m) {
            const int R = wr * 64 + m * 16 + frow;
            af[m] = *(const short8*)&As[cur][R][ca * 8];
        }
        #pragma unroll
        for (int n = 0; n < 4; ++n) {
            const int R = wc * 64 + n * 16 + frow;
            bf[n] = frag8(*(const floatx4*)&Bs[cur][R][c0 * 4],
                          *(const floatx4*)&Bs[cur][R][c1 * 4]);
        }
        #pragma unroll
        for (int m = 0; m < 4; ++m)
            #pragma unroll
            for (int n = 0; n < 4; ++n)
                acc[m][n] = __builtin_amdgcn_mfma_f32_16x16x32_bf16(
                    af[m], bf[n], acc[m][n], 0, 0, 0);

        asm volatile("s_waitcnt lgkmcnt(0)" ::: "memory");
        __builtin_amdgcn_sched_barrier(0);
        __builtin_amdgcn_s_barrier();
    }
#undef STAGE_DN

    const int ccol  = lane & 15;
    const int crow0 = (lane >> 4) * 4;
    float* Ob = out + ((size_t)e * NT + (size_t)tm * 128) * NH + tn * 128;
    #pragma unroll
    for (int m = 0; m < 4; ++m)
        #pragma unroll
        for (int n = 0; n < 4; ++n)
            #pragma unroll
            for (int j = 0; j < 4; ++j) {
                const int row = wr * 64 + m * 16 + crow0 + j;
                const int col = wc * 64 + n * 16 + ccol;
                Ob[(size_t)row * NH + col] = acc[m][n][j];
            }
}

extern "C" void kernel_launch(void* const* d_in, const int* in_sizes, int n_in,
                              void* d_out, int out_size, void* d_ws, size_t ws_size,
                              hipStream_t stream) {
    const float* rin  = (const float*)d_in[0];
    const float* gate = (const float*)d_in[1];
    const float* up   = (const float*)d_in[2];
    const float* down = (const float*)d_in[3];
    float* out = (float*)d_out;
    ushort* hidden = (ushort*)d_ws;

    dim3 blk(256);
    moe_gateup<<<dim3(768), blk, 0, stream>>>(rin, gate, up, hidden);
    moe_down<<<dim3(2048), blk, 0, stream>>>(hidden, down, out);
}

// Round 7
// 410.798 us; speedup vs baseline: 1.0401x; 1.0401x over previous
//
#include <hip/hip_runtime.h>

// Qwen3 MoE experts: per-expert SwiGLU MLP.
//   gate = rin @ gate_proj^T ; up = rin @ up_proj^T
//   hidden = silu(gate) * up ; out = hidden @ down_proj^T
// E=32, T=512, H=2048, I=768. f32 inputs; bf16 MFMA, f32 accum.
//
// R6: ablation-driven split. gateup stuck ~300us under 4 structures while
//     down (single-acc, 64 AGPR) runs 746 TF effective. So: make every GEMM
//     down-shaped. K1 = gate OR up GEMM per block (1536 blocks, one dispatch,
//     64 AGPR, gl_lds f32 dbuf + vmcnt(8)), raw bf16 out to ws. K2 = tiny
//     elementwise silu(g)*u. K3 = down unchanged.
// ws: gate 24MB | up 24MB | hidden 24MB = 72 MB.

#define NE 32
#define NT 512
#define NH 2048
#define NI 768
#define NTI ((size_t)NE * NT * NI)   // 12,582,912 elems per [E,T,I] buffer

typedef short        short8  __attribute__((ext_vector_type(8)));
typedef float        floatx4 __attribute__((ext_vector_type(4)));
typedef __attribute__((address_space(1))) const unsigned int g_u32;
typedef __attribute__((address_space(3))) unsigned int l_u32;

__device__ __forceinline__ void gl_lds16(const void* g, void* l) {
    __builtin_amdgcn_global_load_lds((g_u32*)g, (l_u32*)l, 16, 0, 0);
}

__device__ __forceinline__ unsigned int cvt_pk_bf16(float lo, float hi) {
    unsigned int r;
    asm("v_cvt_pk_bf16_f32 %0, %1, %2" : "=v"(r) : "v"(lo), "v"(hi));
    return r;
}

// two f32x4 (8 consecutive K values) -> one bf16x8 MFMA fragment
__device__ __forceinline__ short8 frag8(floatx4 x0, floatx4 x1) {
    union { unsigned int u[4]; short8 s; } t;
    t.u[0] = cvt_pk_bf16(x0[0], x0[1]);
    t.u[1] = cvt_pk_bf16(x0[2], x0[3]);
    t.u[2] = cvt_pk_bf16(x1[0], x1[1]);
    t.u[3] = cvt_pk_bf16(x1[2], x1[3]);
    return t.s;
}

__device__ __forceinline__ ushort f2bf(float f) {
    union { float f; unsigned int u; } v; v.f = f;
    unsigned int r = v.u + 0x7fffu + ((v.u >> 16) & 1u);
    return (ushort)(r >> 16);
}

__device__ __forceinline__ float bf2f(ushort s) {
    union { unsigned int u; float f; } v; v.u = ((unsigned int)s) << 16;
    return v.f;
}

// ---------------------------------------------------------------------------
// Kernel 1: one GEMM per block — C = rin @ W^T -> bf16 raw (no activation).
// which = wg&1 selects (gate_proj -> gate_ws) or (up_proj -> up_ws).
// BM=128(T) x BN=128(I), BK=32 over H; 4 waves (2x2), 4x4 frags of 16x16.
// LDS: 2 bufs x 2 x f32[128][32] = 64 KB -> 2 blocks/CU. Clone of moe_down.
// ---------------------------------------------------------------------------
__global__ __launch_bounds__(256, 2) void moe_gu(
    const float* __restrict__ rin, const float* __restrict__ gate,
    const float* __restrict__ up, ushort* __restrict__ gate_ws,
    ushort* __restrict__ up_ws)
{
    __shared__ float As[2][128][32];
    __shared__ float Ws[2][128][32];

    // XCD-bijective swizzle: 1536 blocks, chunk 192
    const int bid = blockIdx.x;
    const int wg  = (bid & 7) * 192 + (bid >> 3);
    const int e   = wg / 48;
    const int r48 = wg % 48;
    const int ti  = r48 >> 3;          // 0..5
    const int tm  = (r48 >> 1) & 3;    // 0..3
    const int which = r48 & 1;         // 0=gate 1=up

    const int tid  = threadIdx.x;
    const int lane = tid & 63;
    const int wave = tid >> 6;
    const int wr = wave >> 1, wc = wave & 1;

    const float* Ab = rin + (size_t)e * NT * NH + (size_t)(tm * 128) * NH;
    const float* Wb = (which ? up : gate)
                      + (size_t)e * NI * NH + (size_t)(ti * 128) * NH;
    ushort* dst = which ? up_ws : gate_ws;

    floatx4 acc[4][4];
    #pragma unroll
    for (int m = 0; m < 4; ++m)
        #pragma unroll
        for (int n = 0; n < 4; ++n) acc[m][n] = (floatx4)0.f;

    const int frow = lane & 15;
    const int h    = lane >> 4;
    const int rb   = frow & 7;
    const int c0   = (2 * h) ^ rb;
    const int c1   = (2 * h + 1) ^ rb;
    const int KT = NH / 32;   // 64

    // 8 gl_lds per wave per stage (4 per tile); inst g covers rows [g*8,g*8+8)
#define STAGE_GU(kt, b) do {                                                 \
        const int k0_ = (kt) * 32;                                           \
        _Pragma("unroll")                                                    \
        for (int i = 0; i < 4; ++i) {                                        \
            const int g_ = wave * 4 + i;                                     \
            const int r_ = g_ * 8 + (lane >> 3);                             \
            const int cs_ = (lane & 7) ^ (r_ & 7);                           \
            const size_t so_ = (size_t)r_ * NH + k0_ + cs_ * 4;              \
            gl_lds16(Ab + so_, &As[b][g_ * 8][0]);                           \
            gl_lds16(Wb + so_, &Ws[b][g_ * 8][0]);                           \
        }                                                                    \
    } while (0)

    STAGE_GU(0, 0);

    for (int kt = 0; kt < KT; ++kt) {
        const int cur = kt & 1;
        if (kt + 1 < KT) {
            STAGE_GU(kt + 1, cur ^ 1);
            asm volatile("s_waitcnt vmcnt(8)" ::: "memory");   // tile kt landed
        } else {
            asm volatile("s_waitcnt vmcnt(0)" ::: "memory");
        }
        __builtin_amdgcn_s_barrier();

        short8 af[4], wf[4];
        #pragma unroll
        for (int m = 0; m < 4; ++m) {
            const int R = wr * 64 + m * 16 + frow;
            af[m] = frag8(*(const floatx4*)&As[cur][R][c0 * 4],
                          *(const floatx4*)&As[cur][R][c1 * 4]);
        }
        #pragma unroll
        for (int n = 0; n < 4; ++n) {
            const int R = wc * 64 + n * 16 + frow;
            wf[n] = frag8(*(const floatx4*)&Ws[cur][R][c0 * 4],
                          *(const floatx4*)&Ws[cur][R][c1 * 4]);
        }
        #pragma unroll
        for (int m = 0; m < 4; ++m)
            #pragma unroll
            for (int n = 0; n < 4; ++n)
                acc[m][n] = __builtin_amdgcn_mfma_f32_16x16x32_bf16(
                    af[m], wf[n], acc[m][n], 0, 0, 0);

        asm volatile("s_waitcnt lgkmcnt(0)" ::: "memory");
        __builtin_amdgcn_sched_barrier(0);
        __builtin_amdgcn_s_barrier();
    }
#undef STAGE_GU

    // C/D layout (m89): col=lane&15, row=(lane>>4)*4+reg.
    const int ccol  = lane & 15;
    const int crow0 = (lane >> 4) * 4;
    const size_t obase = ((size_t)e * NT + (size_t)tm * 128) * NI + ti * 128;
    #pragma unroll
    for (int m = 0; m < 4; ++m)
        #pragma unroll
        for (int n = 0; n < 4; ++n)
            #pragma unroll
            for (int j = 0; j < 4; ++j) {
                const int row = wr * 64 + m * 16 + crow0 + j;
                const int col = wc * 64 + n * 16 + ccol;
                dst[obase + (size_t)row * NI + col] = f2bf(acc[m][n][j]);
            }
}

// ---------------------------------------------------------------------------
// Kernel 2: hidden = silu(gate) * up, elementwise over 12.58M bf16.
// ---------------------------------------------------------------------------
__global__ __launch_bounds__(256) void moe_swiglu(
    const ushort* __restrict__ g, const ushort* __restrict__ u,
    ushort* __restrict__ hid)
{
    const int i = blockIdx.x * 256 + threadIdx.x;   // one short8 per thread
    const short8 gv = ((const short8*)g)[i];
    const short8 uv = ((const short8*)u)[i];
    short8 hv;
    #pragma unroll
    for (int j = 0; j < 8; ++j) {
        const float gf = bf2f((ushort)gv[j]);
        const float uf = bf2f((ushort)uv[j]);
        const float hh = (gf / (1.f + __expf(-gf))) * uf;
        hv[j] = (short)f2bf(hh);
    }
    ((short8*)hid)[i] = hv;
}

// ---------------------------------------------------------------------------
// Kernel 3: down projection (unchanged). A = hidden bf16, B = down f32.
// ---------------------------------------------------------------------------
__global__ __launch_bounds__(256, 2) void moe_down(
    const ushort* __restrict__ hidden, const float* __restrict__ down,
    float* __restrict__ out)
{
    __shared__ ushort As[2][128][32];
    __shared__ float  Bs[2][128][32];

    const int bid = blockIdx.x;
    const int wg  = (bid & 7) * (2048 / 8) + (bid >> 3);
    const int e   = wg >> 6;
    const int rem = wg & 63;
    const int tn  = rem & 15;
    const int tm  = rem >> 4;

    const int tid  = threadIdx.x;
    const int lane = tid & 63;
    const int wave = tid >> 6;
    const int wr = wave >> 1, wc = wave & 1;

    const ushort* Ab = hidden + ((size_t)e * NT + (size_t)tm * 128) * NI;
    const float*  Bb = down + (size_t)e * NH * NI + (size_t)(tn * 128) * NI;

    floatx4 acc[4][4];
    #pragma unroll
    for (int m = 0; m < 4; ++m)
        #pragma unroll
        for (int n = 0; n < 4; ++n) acc[m][n] = (floatx4)0.f;

    const int frow = lane & 15;
    const int h    = lane >> 4;
    const int ca   = h ^ (frow & 3);
    const int rb   = frow & 7;
    const int c0   = (2 * h) ^ rb;
    const int c1   = (2 * h + 1) ^ rb;
    const int KT = NI / 32;

#define STAGE_DN(kt, b) do {                                                 \
        const int k0_ = (kt) * 32;                                           \
        _Pragma("unroll")                                                    \
        for (int i = 0; i < 2; ++i) {                                        \
            const int g_ = wave * 2 + i;                                     \
            const int r_ = g_ * 16 + (lane >> 2);                            \
            const int cs_ = (lane & 3) ^ (r_ & 3);                           \
            gl_lds16(Ab + (size_t)r_ * NI + k0_ + cs_ * 8, &As[b][g_ * 16][0]); \
        }                                                                    \
        _Pragma("unroll")                                                    \
        for (int i = 0; i < 4; ++i) {                                        \
            const int g_ = wave * 4 + i;                                     \
            const int r_ = g_ * 8 + (lane >> 3);                             \
            const int cs_ = (lane & 7) ^ (r_ & 7);                           \
            gl_lds16(Bb + (size_t)r_ * NI + k0_ + cs_ * 4, &Bs[b][g_ * 8][0]); \
        }                                                                    \
    } while (0)

    STAGE_DN(0, 0);

    for (int kt = 0; kt < KT; ++kt) {
        const int cur = kt & 1;
        if (kt + 1 < KT) {
            STAGE_DN(kt + 1, cur ^ 1);
            asm volatile("s_waitcnt vmcnt(6)" ::: "memory");
        } else {
            asm volatile("s_waitcnt vmcnt(0)" ::: "memory");
        }
        __builtin_amdgcn_s_barrier();

        short8 af[4], bf[4];
        #pragma unroll
        for (int m = 0; m < 4; ++m) {
            const int R = wr * 64 + m * 16 + frow;
            af[m] = *(const short8*)&As[cur][R][ca * 8];
        }
        #pragma unroll
        for (int n = 0; n < 4; ++n) {
            const int R = wc * 64 + n * 16 + frow;
            bf[n] = frag8(*(const floatx4*)&Bs[cur][R][c0 * 4],
                          *(const floatx4*)&Bs[cur][R][c1 * 4]);
        }
        #pragma unroll
        for (int m = 0; m < 4; ++m)
            #pragma unroll
            for (int n = 0; n < 4; ++n)
                acc[m][n] = __builtin_amdgcn_mfma_f32_16x16x32_bf16(
                    af[m], bf[n], acc[m][n], 0, 0, 0);

        asm volatile("s_waitcnt lgkmcnt(0)" ::: "memory");
        __builtin_amdgcn_sched_barrier(0);
        __builtin_amdgcn_s_barrier();
    }
#undef STAGE_DN

    const int ccol  = lane & 15;
    const int crow0 = (lane >> 4) * 4;
    float* Ob = out + ((size_t)e * NT + (size_t)tm * 128) * NH + tn * 128;
    #pragma unroll
    for (int m = 0; m < 4; ++m)
        #pragma unroll
        for (int n = 0; n < 4; ++n)
            #pragma unroll
            for (int j = 0; j < 4; ++j) {
                const int row = wr * 64 + m * 16 + crow0 + j;
                const int col = wc * 64 + n * 16 + ccol;
                Ob[(size_t)row * NH + col] = acc[m][n][j];
            }
}

extern "C" void kernel_launch(void* const* d_in, const int* in_sizes, int n_in,
                              void* d_out, int out_size, void* d_ws, size_t ws_size,
                              hipStream_t stream) {
    const float* rin  = (const float*)d_in[0];
    const float* gate = (const float*)d_in[1];
    const float* up   = (const float*)d_in[2];
    const float* down = (const float*)d_in[3];
    float* out = (float*)d_out;

    ushort* gate_ws = (ushort*)d_ws;            // [E,T,I] bf16
    ushort* up_ws   = gate_ws + NTI;            // [E,T,I] bf16
    ushort* hidden  = up_ws + NTI;              // [E,T,I] bf16

    dim3 blk(256);
    moe_gu<<<dim3(1536), blk, 0, stream>>>(rin, gate, up, gate_ws, up_ws);
    moe_swiglu<<<dim3((int)(NTI / 8 / 256)), blk, 0, stream>>>(gate_ws, up_ws, hidden);
    moe_down<<<dim3(2048), blk, 0, stream>>>(hidden, down, out);
}